// Round 4
// baseline (1083.368 us; speedup 1.0000x reference)
//
#include <hip/hip_runtime.h>
#include <math.h>

#define B_  64
#define Cc  128
#define L_  3136

typedef __bf16 b8v __attribute__((ext_vector_type(8)));
typedef float  f4v __attribute__((ext_vector_type(4)));

__device__ __forceinline__ f4v mfma16(b8v a, b8v b, f4v c) {
    return __builtin_amdgcn_mfma_f32_16x16x32_bf16(a, b, c, 0, 0, 0);
}
__device__ __forceinline__ int region(int h, int w) {
    int a = (h < 49) ? 0 : ((h < 53) ? 1 : 2);
    int b = (w < 49) ? 0 : ((w < 53) ? 1 : 2);
    return a * 3 + b;
}

// ---------------- workspace layout (bytes) ----------------
// [0, 393216)            bf16 weights: qkv_w | proj_w | fc1_w | fc2_w
// [393216, 655360)       bm f32 [4 wt][4 h][64][64]
// [655360, ...)          Qb bf16 [4096][4][64][32]   (67,108,864 B)
// KB_OFF  = 67,764,224   Kb  same shape
// VT_OFF  = 134,873,088  VTb bf16 [4096][4][32][64]
// OB_OFF  = 201,981,952  Ob  bf16 [4096][64][128]
// LN2_OFF = 269,090,816  ln2b bf16 [200704][128]
// H1_OFF  = 655,360 (alias over Qb/Kb/VTb+Ob-head; dead by K4) [200704][512]
#define BM_OFF   393216ull
#define QB_OFF   655360ull
#define KB_OFF   67764224ull
#define VT_OFF   134873088ull
#define OB_OFF   201981952ull
#define LN2_OFF  269090816ull
#define H1_OFF   655360ull
#define WS_NEED  320471040ull

// ---------------- prep: weights->bf16 + bias/mask table ----------------
__global__ __launch_bounds__(256) void prep_kernel(
    const float* __restrict__ qkv_w, const float* __restrict__ proj_w,
    const float* __restrict__ fc1_w, const float* __restrict__ fc2_w,
    const float* __restrict__ rpb,
    __bf16* __restrict__ wsb, float* __restrict__ bm)
{
    int i = blockIdx.x * 256 + threadIdx.x;
    if      (i <  49152) wsb[i] = (__bf16)qkv_w[i];
    else if (i <  65536) wsb[i] = (__bf16)proj_w[i - 49152];
    else if (i < 131072) wsb[i] = (__bf16)fc1_w[i - 65536];
    else if (i < 196608) wsb[i] = (__bf16)fc2_w[i - 131072];
    else {
        int idx = i - 196608;  // ((wt*4+h)*64+ii)*64+jj
        int jj = idx & 63, ii = (idx >> 6) & 63, h = (idx >> 12) & 3, wt = idx >> 14;
        float v;
        if (jj >= 49)      v = -1e30f;
        else if (ii >= 49) v = 0.f;
        else {
            int ih = ii / 7, iw = ii - ih * 7, jh = jj / 7, jw = jj - jh * 7;
            v = rpb[((ih - jh + 6) * 13 + (iw - jw + 6)) * 4 + h];
            int WH = (wt & 2) ? 49 : 0, WW = (wt & 1) ? 49 : 0;
            if (region(WH + ih, WW + iw) != region(WH + jh, WW + jw)) v -= 100.f;
        }
        bm[idx] = v;
    }
}

// ---------------- K1: LN1 + QKV GEMM, window layout out ----------------
__global__ __launch_bounds__(256) void qkv_kernel(
    const float* __restrict__ x, const float* __restrict__ g1,
    const float* __restrict__ b1, const float* __restrict__ qkv_b,
    const __bf16* __restrict__ wqkv,
    __bf16* __restrict__ qb, __bf16* __restrict__ kb, __bf16* __restrict__ vtb)
{
    __shared__ __bf16 a_s[64 * 136];
    const int tid = threadIdx.x, w = tid >> 6, lane = tid & 63;
    const int quad = lane >> 4, r16 = lane & 15;
    const int win = blockIdx.x, b = win >> 6, wi = win & 63;
    const int wh = wi >> 3, ww = wi & 7;
    const float scale = 0.17677669529663687f;

    // LN1 with shifted gather (2 tokens/iter)
    for (int t = w; t < 49; t += 8) {
        int t2 = t + 4; bool has2 = (t2 < 49);
        int th = t / 7, tw = t - th * 7;
        int sh = wh * 7 + th + 3; if (sh >= 56) sh -= 56;
        int sw = ww * 7 + tw + 3; if (sw >= 56) sw -= 56;
        int rowA = (b * L_ + sh * 56 + sw) * Cc;
        int rowB = rowA;
        if (has2) {
            int th2 = t2 / 7, tw2 = t2 - th2 * 7;
            int sh2 = wh * 7 + th2 + 3; if (sh2 >= 56) sh2 -= 56;
            int sw2 = ww * 7 + tw2 + 3; if (sw2 >= 56) sw2 -= 56;
            rowB = (b * L_ + sh2 * 56 + sw2) * Cc;
        }
        float a0 = x[rowA + lane], a1 = x[rowA + 64 + lane];
        float c0 = x[rowB + lane], c1 = x[rowB + 64 + lane];
        float sA = a0 + a1, qA = a0 * a0 + a1 * a1;
        float sB = c0 + c1, qB = c0 * c0 + c1 * c1;
        for (int off = 32; off; off >>= 1) {
            sA += __shfl_down(sA, off, 64); qA += __shfl_down(qA, off, 64);
            sB += __shfl_down(sB, off, 64); qB += __shfl_down(qB, off, 64);
        }
        sA = __shfl(sA, 0, 64); qA = __shfl(qA, 0, 64);
        sB = __shfl(sB, 0, 64); qB = __shfl(qB, 0, 64);
        {
            float mu = sA * (1.f / 128.f);
            float rs = rsqrtf(qA * (1.f / 128.f) - mu * mu + 1e-5f);
            a_s[t * 136 + lane]      = (__bf16)((a0 - mu) * rs * g1[lane]      + b1[lane]);
            a_s[t * 136 + 64 + lane] = (__bf16)((a1 - mu) * rs * g1[64 + lane] + b1[64 + lane]);
        }
        if (has2) {
            float mu = sB * (1.f / 128.f);
            float rs = rsqrtf(qB * (1.f / 128.f) - mu * mu + 1e-5f);
            a_s[t2 * 136 + lane]      = (__bf16)((c0 - mu) * rs * g1[lane]      + b1[lane]);
            a_s[t2 * 136 + 64 + lane] = (__bf16)((c1 - mu) * rs * g1[64 + lane] + b1[64 + lane]);
        }
    }
    for (int idx = tid; idx < 15 * 128; idx += 256) {
        int rr = idx >> 7, cc = idx & 127;
        a_s[(49 + rr) * 136 + cc] = (__bf16)0.f;
    }
    __syncthreads();

    // wave w owns M-strip rows [16w,16w+16)
    const __bf16* ap = &a_s[(w * 16 + r16) * 136 + quad * 8];
    b8v A0 = *(const b8v*)(ap);
    b8v A1 = *(const b8v*)(ap + 32);
    b8v A2 = *(const b8v*)(ap + 64);
    b8v A3 = *(const b8v*)(ap + 96);

    #pragma unroll
    for (int g = 0; g < 3; g++) {
        for (int j8 = 0; j8 < 8; j8++) {
            int h = j8 >> 1, half = j8 & 1;
            int brow = g * 128 + h * 32 + half * 16;
            const __bf16* bp = wqkv + (brow + r16) * 128 + quad * 8;
            f4v acc = {0.f, 0.f, 0.f, 0.f};
            acc = mfma16(A0, *(const b8v*)(bp),      acc);
            acc = mfma16(A1, *(const b8v*)(bp + 32), acc);
            acc = mfma16(A2, *(const b8v*)(bp + 64), acc);
            acc = mfma16(A3, *(const b8v*)(bp + 96), acc);
            float bias = qkv_b[brow + r16];
            #pragma unroll
            for (int r = 0; r < 4; r++) {
                int tok = w * 16 + quad * 4 + r;
                bool real = tok < 49;
                float v = real ? (acc[r] + bias) : 0.f;
                if (g == 0)
                    qb[((win * 4 + h) * 64 + tok) * 32 + half * 16 + r16] = (__bf16)(v * scale);
                else if (g == 1)
                    kb[((win * 4 + h) * 64 + tok) * 32 + half * 16 + r16] = (__bf16)v;
                else
                    vtb[((win * 4 + h) * 32 + half * 16 + r16) * 64 + tok] = (__bf16)v;
            }
        }
    }
}

// ---------------- K2: attention core, barrier-free, wave = (window, head) ----------------
__global__ __launch_bounds__(256) void attn_core(
    const __bf16* __restrict__ qb, const __bf16* __restrict__ kb,
    const __bf16* __restrict__ vtb, const float* __restrict__ bm,
    __bf16* __restrict__ ob)
{
    __shared__ __bf16 p_s[4][16 * 72];
    const int tid = threadIdx.x, w = tid >> 6, lane = tid & 63;
    const int quad = lane >> 4, r16 = lane & 15;
    const int win = blockIdx.x, wi = win & 63;
    const int wt = (((wi >> 3) == 7) ? 2 : 0) | (((wi & 7) == 7) ? 1 : 0);

    const __bf16* Qp = qb + (size_t)(win * 4 + w) * 64 * 32;
    const __bf16* Kp = kb + (size_t)(win * 4 + w) * 64 * 32;
    const __bf16* Vp = vtb + (size_t)(win * 4 + w) * 32 * 64;
    __bf16* Op = ob + (size_t)win * 64 * 128 + w * 32;
    const float* bmp = bm + ((wt * 4 + w) * 64) * 64;
    __bf16* ps = &p_s[w][0];

    b8v kf[4];
    #pragma unroll
    for (int nt = 0; nt < 4; nt++)
        kf[nt] = *(const b8v*)(Kp + (nt * 16 + r16) * 32 + quad * 8);
    b8v vf[2][2];
    #pragma unroll
    for (int n2 = 0; n2 < 2; n2++)
        #pragma unroll
        for (int ks = 0; ks < 2; ks++)
            vf[n2][ks] = *(const b8v*)(Vp + (n2 * 16 + r16) * 64 + ks * 32 + quad * 8);

    for (int mt = 0; mt < 4; mt++) {
        b8v qf = *(const b8v*)(Qp + (mt * 16 + r16) * 32 + quad * 8);
        f4v s[4];
        #pragma unroll
        for (int nt = 0; nt < 4; nt++) {
            f4v z = {0.f, 0.f, 0.f, 0.f};
            s[nt] = mfma16(qf, kf[nt], z);
        }
        const float* bmr = bmp + (mt * 16 + quad * 4) * 64 + r16;
        #pragma unroll
        for (int nt = 0; nt < 4; nt++)
            #pragma unroll
            for (int r = 0; r < 4; r++)
                s[nt][r] += bmr[r * 64 + nt * 16];
        // softmax (row = quad*4+r, 16 lanes per row)
        {
            float mx[4], sm[4];
            #pragma unroll
            for (int r = 0; r < 4; r++)
                mx[r] = fmaxf(fmaxf(s[0][r], s[1][r]), fmaxf(s[2][r], s[3][r]));
            #pragma unroll
            for (int mk = 1; mk < 16; mk <<= 1)
                #pragma unroll
                for (int r = 0; r < 4; r++)
                    mx[r] = fmaxf(mx[r], __shfl_xor(mx[r], mk, 64));
            #pragma unroll
            for (int r = 0; r < 4; r++) {
                s[0][r] = expf(s[0][r] - mx[r]);
                s[1][r] = expf(s[1][r] - mx[r]);
                s[2][r] = expf(s[2][r] - mx[r]);
                s[3][r] = expf(s[3][r] - mx[r]);
                sm[r] = s[0][r] + s[1][r] + s[2][r] + s[3][r];
            }
            #pragma unroll
            for (int mk = 1; mk < 16; mk <<= 1)
                #pragma unroll
                for (int r = 0; r < 4; r++)
                    sm[r] += __shfl_xor(sm[r], mk, 64);
            #pragma unroll
            for (int r = 0; r < 4; r++) {
                float inv = 1.f / sm[r];
                s[0][r] *= inv; s[1][r] *= inv; s[2][r] *= inv; s[3][r] *= inv;
            }
        }
        // P -> wave-local LDS (D->A transform)
        #pragma unroll
        for (int nt = 0; nt < 4; nt++)
            #pragma unroll
            for (int r = 0; r < 4; r++)
                ps[(quad * 4 + r) * 72 + nt * 16 + r16] = (__bf16)s[nt][r];
        // O strip = P @ V
        #pragma unroll
        for (int n2 = 0; n2 < 2; n2++) {
            f4v o = {0.f, 0.f, 0.f, 0.f};
            #pragma unroll
            for (int ks = 0; ks < 2; ks++) {
                b8v pf = *(const b8v*)(ps + r16 * 72 + ks * 32 + quad * 8);
                o = mfma16(pf, vf[n2][ks], o);
            }
            #pragma unroll
            for (int r = 0; r < 4; r++)
                Op[(mt * 16 + quad * 4 + r) * 128 + n2 * 16 + r16] = (__bf16)o[r];
        }
    }
}

// ---------------- K3: proj + residual + LN2, barrier-free ----------------
__global__ __launch_bounds__(256) void proj_kernel(
    const __bf16* __restrict__ ob, const __bf16* __restrict__ wproj,
    const float* __restrict__ proj_b, const float* __restrict__ x,
    const float* __restrict__ g2, const float* __restrict__ b2,
    float* __restrict__ out, __bf16* __restrict__ ln2b)
{
    const int tid = threadIdx.x, w = tid >> 6, lane = tid & 63;
    const int quad = lane >> 4, r16 = lane & 15;
    const int win = blockIdx.x, b = win >> 6, wi = win & 63;
    const int wh = wi >> 3, ww = wi & 7;

    const __bf16* apg = ob + (size_t)win * 64 * 128 + (w * 16 + r16) * 128 + quad * 8;
    b8v A0 = *(const b8v*)(apg);
    b8v A1 = *(const b8v*)(apg + 32);
    b8v A2 = *(const b8v*)(apg + 64);
    b8v A3 = *(const b8v*)(apg + 96);

    f4v acc[8];
    #pragma unroll
    for (int nt = 0; nt < 8; nt++) {
        const __bf16* bp = wproj + (nt * 16 + r16) * 128 + quad * 8;
        f4v a = {0.f, 0.f, 0.f, 0.f};
        a = mfma16(A0, *(const b8v*)(bp),      a);
        a = mfma16(A1, *(const b8v*)(bp + 32), a);
        a = mfma16(A2, *(const b8v*)(bp + 64), a);
        a = mfma16(A3, *(const b8v*)(bp + 96), a);
        acc[nt] = a;
    }

    int offr[4]; bool real[4];
    #pragma unroll
    for (int r = 0; r < 4; r++) {
        int tok = w * 16 + quad * 4 + r;
        real[r] = tok < 49;
        int th = tok / 7, tw = tok - th * 7;
        int sh = wh * 7 + th + 3; if (sh >= 56) sh -= 56;
        int sw = ww * 7 + tw + 3; if (sw >= 56) sw -= 56;
        offr[r] = (b * L_ + sh * 56 + sw) * Cc;
    }
    // residual: x1 into acc, write out
    #pragma unroll
    for (int nt = 0; nt < 8; nt++) {
        int col = nt * 16 + r16;
        float pb = proj_b[col];
        #pragma unroll
        for (int r = 0; r < 4; r++) {
            if (real[r]) {
                float v = x[offr[r] + col] + acc[nt][r] + pb;
                acc[nt][r] = v;
                out[offr[r] + col] = v;
            } else acc[nt][r] = 0.f;
        }
    }
    // LN2 per row (16 lanes of a row share quad; reduce over r16 via xor 1,2,4,8)
    float mu[4], rs[4];
    #pragma unroll
    for (int r = 0; r < 4; r++) {
        float sm = 0.f, sq = 0.f;
        #pragma unroll
        for (int nt = 0; nt < 8; nt++) { sm += acc[nt][r]; sq += acc[nt][r] * acc[nt][r]; }
        #pragma unroll
        for (int mk = 1; mk < 16; mk <<= 1) {
            sm += __shfl_xor(sm, mk, 64);
            sq += __shfl_xor(sq, mk, 64);
        }
        mu[r] = sm * (1.f / 128.f);
        rs[r] = rsqrtf(sq * (1.f / 128.f) - mu[r] * mu[r] + 1e-5f);
    }
    #pragma unroll
    for (int nt = 0; nt < 8; nt++) {
        int col = nt * 16 + r16;
        float gg = g2[col], bb = b2[col];
        #pragma unroll
        for (int r = 0; r < 4; r++)
            if (real[r])
                ln2b[offr[r] + col] = (__bf16)((acc[nt][r] - mu[r]) * rs[r] * gg + bb);
    }
}

// ---------------- K4: fc1 + exact GELU, barrier-free ----------------
__global__ __launch_bounds__(256) void fc1_kernel(
    const __bf16* __restrict__ ln2b, const __bf16* __restrict__ wfc1,
    const float* __restrict__ fc1_b, __bf16* __restrict__ h1b)
{
    const int tid = threadIdx.x, w = tid >> 6, lane = tid & 63;
    const int quad = lane >> 4, r16 = lane & 15;
    const int t0 = blockIdx.x * 64;

    const __bf16* apg = ln2b + (size_t)(t0 + w * 16 + r16) * 128 + quad * 8;
    b8v A0 = *(const b8v*)(apg);
    b8v A1 = *(const b8v*)(apg + 32);
    b8v A2 = *(const b8v*)(apg + 64);
    b8v A3 = *(const b8v*)(apg + 96);

    for (int nt = 0; nt < 32; nt++) {
        const __bf16* bp = wfc1 + (nt * 16 + r16) * 128 + quad * 8;
        f4v acc = {0.f, 0.f, 0.f, 0.f};
        acc = mfma16(A0, *(const b8v*)(bp),      acc);
        acc = mfma16(A1, *(const b8v*)(bp + 32), acc);
        acc = mfma16(A2, *(const b8v*)(bp + 64), acc);
        acc = mfma16(A3, *(const b8v*)(bp + 96), acc);
        float bias = fc1_b[nt * 16 + r16];
        #pragma unroll
        for (int r = 0; r < 4; r++) {
            float v = acc[r] + bias;
            v = 0.5f * v * (1.f + erff(v * 0.70710678118654752f));
            h1b[(size_t)(t0 + w * 16 + quad * 4 + r) * 512 + nt * 16 + r16] = (__bf16)v;
        }
    }
}

// ---------------- K5: fc2 + residual RMW, barrier-free ----------------
__global__ __launch_bounds__(256) void fc2_kernel(
    const __bf16* __restrict__ h1b, const __bf16* __restrict__ wfc2,
    const float* __restrict__ fc2_b, float* __restrict__ out)
{
    const int tid = threadIdx.x, w = tid >> 6, lane = tid & 63;
    const int quad = lane >> 4, r16 = lane & 15;
    const int t0 = blockIdx.x * 64;

    const __bf16* apg = h1b + (size_t)(t0 + w * 16 + r16) * 512 + quad * 8;
    b8v ha[16];
    #pragma unroll
    for (int ks = 0; ks < 16; ks++)
        ha[ks] = *(const b8v*)(apg + ks * 32);

    for (int nt = 0; nt < 8; nt++) {
        const __bf16* bp = wfc2 + (nt * 16 + r16) * 512 + quad * 8;
        f4v acc = {0.f, 0.f, 0.f, 0.f};
        #pragma unroll
        for (int ks = 0; ks < 16; ks++)
            acc = mfma16(ha[ks], *(const b8v*)(bp + ks * 32), acc);
        int col = nt * 16 + r16;
        float bias = fc2_b[col];
        #pragma unroll
        for (int r = 0; r < 4; r++) {
            size_t off = (size_t)(t0 + w * 16 + quad * 4 + r) * 128 + col;
            out[off] += acc[r] + bias;
        }
    }
}

// ================= fallback: round-3 fused kernel (ws too small) =================
__global__ __launch_bounds__(256, 3) void swin_kernel(
    const float* __restrict__ x,
    const float* __restrict__ g1, const float* __restrict__ b1,
    const float* __restrict__ qkv_b, const float* __restrict__ proj_b,
    const float* __restrict__ g2, const float* __restrict__ b2,
    const float* __restrict__ fc1_b, const float* __restrict__ fc2_b,
    const __bf16* __restrict__ wqkv, const __bf16* __restrict__ wproj,
    const __bf16* __restrict__ wfc1, const __bf16* __restrict__ wfc2,
    const float* __restrict__ bm,
    float* __restrict__ out)
{
    __shared__ __bf16 a_s[64 * 136];
    __shared__ __align__(16) char u_s[33280];
    __bf16* QKs = (__bf16*)u_s;
    __bf16* VTs = (__bf16*)(u_s + 9216);
    __bf16* PSs = (__bf16*)(u_s + 13824);
    __bf16* OSs = (__bf16*)u_s;
    __bf16* H1s = (__bf16*)u_s;

    const int tid = threadIdx.x, w = tid >> 6, lane = tid & 63;
    const int quad = lane >> 4, r16 = lane & 15;
    const int blk = blockIdx.x, b = blk >> 6, wi = blk & 63;
    const int wh = wi >> 3, ww = wi & 7;
    const int wt = ((wh == 7) ? 2 : 0) | ((ww == 7) ? 1 : 0);
    const float scale = 0.17677669529663687f;

    for (int t = w; t < 49; t += 8) {
        int t2 = t + 4; bool has2 = (t2 < 49);
        int th = t / 7, tw = t - th * 7;
        int sh = wh * 7 + th + 3; if (sh >= 56) sh -= 56;
        int sw = ww * 7 + tw + 3; if (sw >= 56) sw -= 56;
        int rowA = (b * L_ + sh * 56 + sw) * Cc;
        int rowB = rowA;
        if (has2) {
            int th2 = t2 / 7, tw2 = t2 - th2 * 7;
            int sh2 = wh * 7 + th2 + 3; if (sh2 >= 56) sh2 -= 56;
            int sw2 = ww * 7 + tw2 + 3; if (sw2 >= 56) sw2 -= 56;
            rowB = (b * L_ + sh2 * 56 + sw2) * Cc;
        }
        float a0 = x[rowA + lane], a1 = x[rowA + 64 + lane];
        float c0 = x[rowB + lane], c1 = x[rowB + 64 + lane];
        float sA = a0 + a1, qA = a0 * a0 + a1 * a1;
        float sB = c0 + c1, qB = c0 * c0 + c1 * c1;
        for (int off = 32; off; off >>= 1) {
            sA += __shfl_down(sA, off, 64); qA += __shfl_down(qA, off, 64);
            sB += __shfl_down(sB, off, 64); qB += __shfl_down(qB, off, 64);
        }
        sA = __shfl(sA, 0, 64); qA = __shfl(qA, 0, 64);
        sB = __shfl(sB, 0, 64); qB = __shfl(qB, 0, 64);
        {
            float mu = sA * (1.f / 128.f);
            float rs = rsqrtf(qA * (1.f / 128.f) - mu * mu + 1e-5f);
            a_s[t * 136 + lane]      = (__bf16)((a0 - mu) * rs * g1[lane]      + b1[lane]);
            a_s[t * 136 + 64 + lane] = (__bf16)((a1 - mu) * rs * g1[64 + lane] + b1[64 + lane]);
        }
        if (has2) {
            float mu = sB * (1.f / 128.f);
            float rs = rsqrtf(qB * (1.f / 128.f) - mu * mu + 1e-5f);
            a_s[t2 * 136 + lane]      = (__bf16)((c0 - mu) * rs * g1[lane]      + b1[lane]);
            a_s[t2 * 136 + 64 + lane] = (__bf16)((c1 - mu) * rs * g1[64 + lane] + b1[64 + lane]);
        }
    }
    for (int idx = tid; idx < 15 * 128; idx += 256) {
        int rr = idx >> 7, cc = idx & 127;
        a_s[(49 + rr) * 136 + cc] = (__bf16)0.f;
    }
    __syncthreads();

    f4v o_acc[4][2];
    #pragma unroll
    for (int h = 0; h < 4; h++)
        #pragma unroll
        for (int n = 0; n < 2; n++)
            o_acc[h][n] = (f4v){0.f, 0.f, 0.f, 0.f};

    const float* bmw = bm + wt * 4 * 4096;

    for (int h = 0; h < 4; h++) {
        {
            const __bf16* ap = &a_s[(w * 16 + r16) * 136 + quad * 8];
            b8v A0 = *(const b8v*)(ap);
            b8v A1 = *(const b8v*)(ap + 32);
            b8v A2 = *(const b8v*)(ap + 64);
            b8v A3 = *(const b8v*)(ap + 96);
            #pragma unroll
            for (int nt = 0; nt < 6; nt++) {
                int base = (nt < 2) ? (h * 32 + nt * 16)
                         : (nt < 4) ? (128 + h * 32 + (nt - 2) * 16)
                                    : (256 + h * 32 + (nt - 4) * 16);
                const __bf16* bp = wqkv + (base + r16) * 128 + quad * 8;
                f4v acc = {0.f, 0.f, 0.f, 0.f};
                acc = mfma16(A0, *(const b8v*)(bp),      acc);
                acc = mfma16(A1, *(const b8v*)(bp + 32), acc);
                acc = mfma16(A2, *(const b8v*)(bp + 64), acc);
                acc = mfma16(A3, *(const b8v*)(bp + 96), acc);
                float bias = qkv_b[base + r16];
                #pragma unroll
                for (int r = 0; r < 4; r++) {
                    int m = w * 16 + quad * 4 + r;
                    float v = acc[r] + bias;
                    if (nt < 2)      QKs[m * 72 + nt * 16 + r16]            = (__bf16)(v * scale);
                    else if (nt < 4) QKs[m * 72 + 32 + (nt - 2) * 16 + r16] = (__bf16)v;
                    else             VTs[((nt - 4) * 16 + r16) * 72 + m]    = (__bf16)v;
                }
            }
        }
        __syncthreads();

        f4v s[4];
        {
            b8v qf = *(const b8v*)&QKs[(w * 16 + r16) * 72 + quad * 8];
            #pragma unroll
            for (int nt = 0; nt < 4; nt++) {
                b8v kf = *(const b8v*)&QKs[(nt * 16 + r16) * 72 + 32 + quad * 8];
                f4v z = {0.f, 0.f, 0.f, 0.f};
                s[nt] = mfma16(qf, kf, z);
            }
            const float* bmp = bmw + h * 4096 + (w * 16 + quad * 4) * 64 + r16;
            #pragma unroll
            for (int nt = 0; nt < 4; nt++)
                #pragma unroll
                for (int r = 0; r < 4; r++)
                    s[nt][r] += bmp[r * 64 + nt * 16];
        }
        {
            float mx[4], sm[4];
            #pragma unroll
            for (int r = 0; r < 4; r++)
                mx[r] = fmaxf(fmaxf(s[0][r], s[1][r]), fmaxf(s[2][r], s[3][r]));
            #pragma unroll
            for (int mk = 1; mk < 16; mk <<= 1)
                #pragma unroll
                for (int r = 0; r < 4; r++)
                    mx[r] = fmaxf(mx[r], __shfl_xor(mx[r], mk, 64));
            #pragma unroll
            for (int r = 0; r < 4; r++) {
                s[0][r] = expf(s[0][r] - mx[r]);
                s[1][r] = expf(s[1][r] - mx[r]);
                s[2][r] = expf(s[2][r] - mx[r]);
                s[3][r] = expf(s[3][r] - mx[r]);
                sm[r] = s[0][r] + s[1][r] + s[2][r] + s[3][r];
            }
            #pragma unroll
            for (int mk = 1; mk < 16; mk <<= 1)
                #pragma unroll
                for (int r = 0; r < 4; r++)
                    sm[r] += __shfl_xor(sm[r], mk, 64);
            #pragma unroll
            for (int r = 0; r < 4; r++) {
                float inv = 1.f / sm[r];
                s[0][r] *= inv; s[1][r] *= inv; s[2][r] *= inv; s[3][r] *= inv;
            }
        }
        #pragma unroll
        for (int nt = 0; nt < 4; nt++)
            #pragma unroll
            for (int r = 0; r < 4; r++)
                PSs[(w * 16 + quad * 4 + r) * 72 + nt * 16 + r16] = (__bf16)s[nt][r];

        #pragma unroll
        for (int nt = 0; nt < 2; nt++)
            #pragma unroll
            for (int ks = 0; ks < 2; ks++) {
                b8v pf = *(const b8v*)&PSs[(w * 16 + r16) * 72 + ks * 32 + quad * 8];
                b8v vfr = *(const b8v*)&VTs[(nt * 16 + r16) * 72 + ks * 32 + quad * 8];
                o_acc[h][nt] = mfma16(pf, vfr, o_acc[h][nt]);
            }
        __syncthreads();
    }

    #pragma unroll
    for (int h = 0; h < 4; h++)
        #pragma unroll
        for (int nt = 0; nt < 2; nt++)
            #pragma unroll
            for (int r = 0; r < 4; r++)
                OSs[(w * 16 + quad * 4 + r) * 136 + h * 32 + nt * 16 + r16] = (__bf16)o_acc[h][nt][r];
    __syncthreads();

    {
        const __bf16* ap = &OSs[(w * 16 + r16) * 136 + quad * 8];
        b8v A0 = *(const b8v*)(ap);
        b8v A1 = *(const b8v*)(ap + 32);
        b8v A2 = *(const b8v*)(ap + 64);
        b8v A3 = *(const b8v*)(ap + 96);
        #pragma unroll
        for (int nt = 0; nt < 8; nt++) {
            const __bf16* bp = wproj + (nt * 16 + r16) * 128 + quad * 8;
            f4v acc = {0.f, 0.f, 0.f, 0.f};
            acc = mfma16(A0, *(const b8v*)(bp),      acc);
            acc = mfma16(A1, *(const b8v*)(bp + 32), acc);
            acc = mfma16(A2, *(const b8v*)(bp + 64), acc);
            acc = mfma16(A3, *(const b8v*)(bp + 96), acc);
            int col = nt * 16 + r16;
            float pb = proj_b[col];
            #pragma unroll
            for (int r = 0; r < 4; r++) {
                int t = w * 16 + quad * 4 + r;
                float x1v = 0.f;
                if (t < 49) {
                    int th = t / 7, tw = t - th * 7;
                    int sh = wh * 7 + th + 3; if (sh >= 56) sh -= 56;
                    int sw = ww * 7 + tw + 3; if (sw >= 56) sw -= 56;
                    int off = (b * L_ + sh * 56 + sw) * Cc + col;
                    x1v = x[off] + acc[r] + pb;
                    out[off] = x1v;
                }
                a_s[t * 136 + col] = (__bf16)x1v;
            }
        }
    }
    __syncthreads();

    for (int t = w; t < 49; t += 8) {
        int t2 = t + 4; bool has2 = (t2 < 49);
        int tB = has2 ? t2 : t;
        float a0 = (float)a_s[t * 136 + lane],  a1 = (float)a_s[t * 136 + 64 + lane];
        float c0 = (float)a_s[tB * 136 + lane], c1 = (float)a_s[tB * 136 + 64 + lane];
        float sA = a0 + a1, qA = a0 * a0 + a1 * a1;
        float sB = c0 + c1, qB = c0 * c0 + c1 * c1;
        for (int off = 32; off; off >>= 1) {
            sA += __shfl_down(sA, off, 64); qA += __shfl_down(qA, off, 64);
            sB += __shfl_down(sB, off, 64); qB += __shfl_down(qB, off, 64);
        }
        sA = __shfl(sA, 0, 64); qA = __shfl(qA, 0, 64);
        sB = __shfl(sB, 0, 64); qB = __shfl(qB, 0, 64);
        {
            float mu = sA * (1.f / 128.f);
            float rs = rsqrtf(qA * (1.f / 128.f) - mu * mu + 1e-5f);
            a_s[t * 136 + lane]      = (__bf16)((a0 - mu) * rs * g2[lane]      + b2[lane]);
            a_s[t * 136 + 64 + lane] = (__bf16)((a1 - mu) * rs * g2[64 + lane] + b2[64 + lane]);
        }
        if (has2) {
            float mu = sB * (1.f / 128.f);
            float rs = rsqrtf(qB * (1.f / 128.f) - mu * mu + 1e-5f);
            a_s[t2 * 136 + lane]      = (__bf16)((c0 - mu) * rs * g2[lane]      + b2[lane]);
            a_s[t2 * 136 + 64 + lane] = (__bf16)((c1 - mu) * rs * g2[64 + lane] + b2[64 + lane]);
        }
    }
    __syncthreads();

    #pragma unroll
    for (int ch = 0; ch < 2; ch++) {
        {
            const __bf16* ap0 = &a_s[(ch * 32 + r16) * 136 + quad * 8];
            const __bf16* ap1 = &a_s[(ch * 32 + 16 + r16) * 136 + quad * 8];
            b8v A00 = *(const b8v*)(ap0), A01 = *(const b8v*)(ap0 + 32),
                A02 = *(const b8v*)(ap0 + 64), A03 = *(const b8v*)(ap0 + 96);
            b8v A10 = *(const b8v*)(ap1), A11 = *(const b8v*)(ap1 + 32),
                A12 = *(const b8v*)(ap1 + 64), A13 = *(const b8v*)(ap1 + 96);
            #pragma unroll
            for (int k = 0; k < 8; k++) {
                int nt = w * 8 + k;
                const __bf16* bp = wfc1 + (nt * 16 + r16) * 128 + quad * 8;
                b8v Bf0 = *(const b8v*)(bp), Bf1 = *(const b8v*)(bp + 32),
                    Bf2 = *(const b8v*)(bp + 64), Bf3 = *(const b8v*)(bp + 96);
                f4v acc0 = {0.f, 0.f, 0.f, 0.f}, acc1 = {0.f, 0.f, 0.f, 0.f};
                acc0 = mfma16(A00, Bf0, acc0); acc1 = mfma16(A10, Bf0, acc1);
                acc0 = mfma16(A01, Bf1, acc0); acc1 = mfma16(A11, Bf1, acc1);
                acc0 = mfma16(A02, Bf2, acc0); acc1 = mfma16(A12, Bf2, acc1);
                acc0 = mfma16(A03, Bf3, acc0); acc1 = mfma16(A13, Bf3, acc1);
                float bias = fc1_b[nt * 16 + r16];
                #pragma unroll
                for (int r = 0; r < 4; r++) {
                    float v0 = acc0[r] + bias;
                    float v1 = acc1[r] + bias;
                    v0 = 0.5f * v0 * (1.f + erff(v0 * 0.70710678118654752f));
                    v1 = 0.5f * v1 * (1.f + erff(v1 * 0.70710678118654752f));
                    H1s[(quad * 4 + r) * 520 + nt * 16 + r16]      = (__bf16)v0;
                    H1s[(16 + quad * 4 + r) * 520 + nt * 16 + r16] = (__bf16)v1;
                }
            }
        }
        __syncthreads();
        {
            f4v acc00 = {0.f,0.f,0.f,0.f}, acc01 = {0.f,0.f,0.f,0.f};
            f4v acc10 = {0.f,0.f,0.f,0.f}, acc11 = {0.f,0.f,0.f,0.f};
            const __bf16* bp0 = wfc2 + (w * 16 + r16) * 512 + quad * 8;
            const __bf16* bp1 = wfc2 + ((w + 4) * 16 + r16) * 512 + quad * 8;
            const __bf16* ap0 = &H1s[r16 * 520 + quad * 8];
            const __bf16* ap1 = &H1s[(16 + r16) * 520 + quad * 8];
            #pragma unroll
            for (int ks = 0; ks < 16; ks++) {
                b8v Af0 = *(const b8v*)(ap0 + ks * 32);
                b8v Af1 = *(const b8v*)(ap1 + ks * 32);
                b8v Bf0 = *(const b8v*)(bp0 + ks * 32);
                b8v Bf1 = *(const b8v*)(bp1 + ks * 32);
                acc00 = mfma16(Af0, Bf0, acc00);
                acc10 = mfma16(Af1, Bf0, acc10);
                acc01 = mfma16(Af0, Bf1, acc01);
                acc11 = mfma16(Af1, Bf1, acc11);
            }
            float fb0 = fc2_b[w * 16 + r16];
            float fb1 = fc2_b[64 + w * 16 + r16];
            #pragma unroll
            for (int mt = 0; mt < 2; mt++) {
                #pragma unroll
                for (int r = 0; r < 4; r++) {
                    int t = ch * 32 + mt * 16 + quad * 4 + r;
                    if (t < 49) {
                        int th = t / 7, tw = t - th * 7;
                        int sh = wh * 7 + th + 3; if (sh >= 56) sh -= 56;
                        int sw = ww * 7 + tw + 3; if (sw >= 56) sw -= 56;
                        int off = (b * L_ + sh * 56 + sw) * Cc;
                        float v0 = mt ? acc10[r] : acc00[r];
                        float v1 = mt ? acc11[r] : acc01[r];
                        out[off + w * 16 + r16]      += v0 + fb0;
                        out[off + 64 + w * 16 + r16] += v1 + fb1;
                    }
                }
            }
        }
        __syncthreads();
    }
}

extern "C" void kernel_launch(void* const* d_in, const int* in_sizes, int n_in,
                              void* d_out, int out_size, void* d_ws, size_t ws_size,
                              hipStream_t stream) {
    // 0 x, 1 ln1_g, 2 ln1_b, 3 qkv_w, 4 qkv_b, 5 rpb_table, 6 proj_w, 7 proj_b,
    // 8 ln2_g, 9 ln2_b, 10 fc1_w, 11 fc1_b, 12 fc2_w, 13 fc2_b
    __bf16* wsb = (__bf16*)d_ws;
    float*  bmp = (float*)((char*)d_ws + BM_OFF);
    prep_kernel<<<1024, 256, 0, stream>>>(
        (const float*)d_in[3], (const float*)d_in[6],
        (const float*)d_in[10], (const float*)d_in[12],
        (const float*)d_in[5], wsb, bmp);

    if (ws_size >= WS_NEED) {
        __bf16* qb   = (__bf16*)((char*)d_ws + QB_OFF);
        __bf16* kb   = (__bf16*)((char*)d_ws + KB_OFF);
        __bf16* vtb  = (__bf16*)((char*)d_ws + VT_OFF);
        __bf16* ob   = (__bf16*)((char*)d_ws + OB_OFF);
        __bf16* ln2b = (__bf16*)((char*)d_ws + LN2_OFF);
        __bf16* h1b  = (__bf16*)((char*)d_ws + H1_OFF);
        qkv_kernel<<<4096, 256, 0, stream>>>(
            (const float*)d_in[0], (const float*)d_in[1], (const float*)d_in[2],
            (const float*)d_in[4], wsb, qb, kb, vtb);
        attn_core<<<4096, 256, 0, stream>>>(qb, kb, vtb, bmp, ob);
        proj_kernel<<<4096, 256, 0, stream>>>(
            ob, wsb + 49152, (const float*)d_in[7], (const float*)d_in[0],
            (const float*)d_in[8], (const float*)d_in[9], (float*)d_out, ln2b);
        fc1_kernel<<<3136, 256, 0, stream>>>(
            ln2b, wsb + 65536, (const float*)d_in[11], h1b);
        fc2_kernel<<<3136, 256, 0, stream>>>(
            h1b, wsb + 131072, (const float*)d_in[13], (float*)d_out);
    } else {
        swin_kernel<<<4096, 256, 0, stream>>>(
            (const float*)d_in[0],
            (const float*)d_in[1], (const float*)d_in[2],
            (const float*)d_in[4], (const float*)d_in[7],
            (const float*)d_in[8], (const float*)d_in[9],
            (const float*)d_in[11], (const float*)d_in[13],
            wsb, wsb + 49152, wsb + 65536, wsb + 131072,
            bmp, (float*)d_out);
    }
}